// Round 8
// baseline (368.699 us; speedup 1.0000x reference)
//
#include <hip/hip_runtime.h>

#define NPIX 9216
#define CIN 72
#define CP 96
#define SPLITS 8
#define JCHUNK (NPIX / SPLITS)   // 1152
#define JTILES (JCHUNK / 64)     // 18
// p = exp2(s*log2e - 32*log2e)  (fixed softmax shift 32; safe to s<120)
#define L2E   1.44269504088896f
#define EXPB  46.1662413084468f

typedef __attribute__((ext_vector_type(8))) short bf16x8;
typedef __attribute__((ext_vector_type(8))) _Float16 f16x8;
typedef __attribute__((ext_vector_type(4))) float f32x4;

#define MFMA_BF16(A,B,C) __builtin_amdgcn_mfma_f32_16x16x32_bf16(A,B,C,0,0,0)
#define MFMA_F16(A,B,C)  __builtin_amdgcn_mfma_f32_16x16x32_f16(A,B,C,0,0,0)

static __device__ __forceinline__ unsigned short f2bf(float f) {
  unsigned u = __float_as_uint(f);
  u += 0x7fffu + ((u >> 16) & 1u);
  return (unsigned short)(u >> 16);
}
static __device__ __forceinline__ float bf2f(unsigned short h) {
  return __uint_as_float(((unsigned)h) << 16);
}
static __device__ __forceinline__ unsigned short f2h(float f) {
  _Float16 h = (_Float16)f;
  return *(unsigned short*)&h;
}
// pack trunc-bf16 of (lo,hi) into one dword: [lo.hi16 | hi.hi16]
static __device__ __forceinline__ unsigned pack_bf_trunc(float lo, float hi) {
  return (__float_as_uint(lo) >> 16) | (__float_as_uint(hi) & 0xffff0000u);
}

// ---------------------------------------------------------------------------
// Kernel 0: W prep — split-bf16 (hi/lo) of Wq/Wk/Wv, padded to [80][96].
// ---------------------------------------------------------------------------
__global__ __launch_bounds__(256) void wprep_kernel(
    const float* __restrict__ Wq, const float* __restrict__ Wk,
    const float* __restrict__ Wv,
    unsigned short* __restrict__ WH, unsigned short* __restrict__ WL)
{
  int id = blockIdx.x * 256 + threadIdx.x;
  if (id >= 3 * 80 * 96) return;
  int mat = id / (80 * 96);
  int rem = id % (80 * 96);
  int d = rem / 96, c = rem % 96;
  const float* W = (mat == 0) ? Wq : (mat == 1) ? Wk : Wv;
  float v = (d < 72 && c < 72) ? W[d * 72 + c] : 0.f;
  unsigned short hi = f2bf(v);
  WH[id] = hi;
  WL[id] = f2bf(v - bf2f(hi));
}

// ---------------------------------------------------------------------------
// Kernel 1: QKV projection, split-bf16 MFMA GEMM, one wave per block (16 px).
// ---------------------------------------------------------------------------
#define XTS 104   // LDS row stride (ushorts), 208 B

__global__ __launch_bounds__(64) void qkv_kernel(
    const float* __restrict__ x,
    const unsigned short* __restrict__ WH, const unsigned short* __restrict__ WL,
    const float* __restrict__ bq, const float* __restrict__ bk,
    const float* __restrict__ bv,
    unsigned short* __restrict__ QH, unsigned short* __restrict__ KH,
    unsigned short* __restrict__ VG)
{
  __shared__ __align__(16) unsigned short xth[16 * XTS];
  __shared__ __align__(16) unsigned short xtl[16 * XTS];
  __shared__ __align__(16) unsigned short obuf[16 * XTS];

  const int t    = threadIdx.x;
  const int quad = t >> 4;
  const int l15  = t & 15;
  const int bid  = blockIdx.x;
  const int b    = bid / 576;
  const int n0   = (bid % 576) * 16;

  for (int e = t; e < 72 * 16; e += 64) {
    int c = e >> 4, px = e & 15;
    float f = x[((size_t)b * CIN + c) * NPIX + n0 + px];
    unsigned short hi = f2bf(f);
    xth[px * XTS + c] = hi;
    xtl[px * XTS + c] = f2bf(f - bf2f(hi));
  }
  for (int e = t; e < 24 * 16; e += 64) {
    int c = 72 + (e >> 4), px = e & 15;
    xth[px * XTS + c] = 0;
    xtl[px * XTS + c] = 0;
  }
  __syncthreads();

  bf16x8 xbh[3], xbl[3];
#pragma unroll
  for (int ks = 0; ks < 3; ++ks) {
    int off = l15 * XTS + ks * 32 + quad * 8;
    xbh[ks] = *(const bf16x8*)(xth + off);
    xbl[ks] = *(const bf16x8*)(xtl + off);
  }

  for (int mat = 0; mat < 3; ++mat) {
    const unsigned short* wh = WH + mat * 80 * 96;
    const unsigned short* wl = WL + mat * 80 * 96;
    const float* bias = (mat == 0) ? bq : (mat == 1) ? bk : bv;

    f32x4 acc[5];
#pragma unroll
    for (int dm = 0; dm < 5; ++dm) {
      acc[dm] = (f32x4){0.f, 0.f, 0.f, 0.f};
#pragma unroll
      for (int ks = 0; ks < 3; ++ks) {
        bf16x8 ah = *(const bf16x8*)(wh + (dm * 16 + l15) * 96 + ks * 32 + quad * 8);
        bf16x8 al = *(const bf16x8*)(wl + (dm * 16 + l15) * 96 + ks * 32 + quad * 8);
        acc[dm] = MFMA_BF16(ah, xbh[ks], acc[dm]);
        acc[dm] = MFMA_BF16(ah, xbl[ks], acc[dm]);
        acc[dm] = MFMA_BF16(al, xbh[ks], acc[dm]);
      }
    }

    if (mat < 2) {
      __syncthreads();                 // obuf free
#pragma unroll
      for (int dm = 0; dm < 5; ++dm)
#pragma unroll
        for (int r = 0; r < 4; ++r) {
          int d = dm * 16 + quad * 4 + r;
          float v = acc[dm][r] + (d < 72 ? bias[d] : 0.f);
          obuf[l15 * XTS + d] = f2h(v);
        }
      __syncthreads();
      unsigned short* outp = (mat == 0) ? QH : KH;
      const size_t ob = ((size_t)b * NPIX + n0) * CP;
      uint4 z; z.x = z.y = z.z = z.w = 0u;
      for (int f = t; f < 192; f += 64) {
        int row = f / 12, col = f % 12;
        *(uint4*)(outp + ob + (size_t)row * CP + col * 8) =
            (col < 10) ? *(const uint4*)(obuf + row * XTS + col * 8) : z;
      }
    } else {
#pragma unroll
      for (int dm = 0; dm < 5; ++dm)
#pragma unroll
        for (int r = 0; r < 4; ++r) {
          int d = dm * 16 + quad * 4 + r;
          float v = acc[dm][r] + (d < 72 ? bias[d] : 0.f);
          VG[((size_t)b * 80 + d) * NPIX + n0 + l15] = f2bf(v);
        }
    }
  }
}

// ---------------------------------------------------------------------------
// Kernel 2: fused flash attention — NO K/V LDS staging, NO K-loop barriers.
// K fragments (S^T A-operand) and V fragments (PV B-operand) are 16B-
// contiguous in the global KH[n][c] / VG[c][n] layouts -> direct global b128
// loads (16x64B fully-utilized transactions), served by XCD-affine L2 chunk
// (sp = bid&7) and L1 (22 KB tile working set). LDS holds only the per-wave
// P tiles (write b64 -> read b128, same wave, lgkmcnt only).
// Grid 768; 4 waves x 48 rows. LDS 27.6 KB -> 4-5 blocks/CU.
// ---------------------------------------------------------------------------
#define PSP 72    // p tile stride

__global__ __launch_bounds__(256, 4) void flash_kernel(
    const unsigned short* __restrict__ QH, const unsigned short* __restrict__ KH,
    const unsigned short* __restrict__ VG,
    unsigned short* __restrict__ OPH, float* __restrict__ LPART)
{
  __shared__ __align__(16) union {
    unsigned short ps[4][48 * PSP];  // 27,648 B (K-loop, per-wave slots)
    float eb[4][16 * 73];            // 18,688 B (epilogue only)
  } u;

  const int t    = threadIdx.x;
  const int w    = t >> 6;
  const int lane = t & 63;
  const int quad = lane >> 4;
  const int l15  = lane & 15;

  const int bid  = blockIdx.x;
  const int sp   = bid & 7;
  const int slot = bid >> 3;
  const int b    = slot / 48;
  const int it   = slot % 48;
  const int i0w  = it * 192 + w * 48;

  // Q fragments (B-operand of S^T scores: n=l15=i, k=quad*8+c)
  f16x8 qh[3][3];
#pragma unroll
  for (int mi = 0; mi < 3; ++mi)
#pragma unroll
    for (int ks = 0; ks < 3; ++ks) {
      size_t off = ((size_t)b * NPIX + i0w + mi * 16 + l15) * CP + ks * 32 + quad * 8;
      qh[mi][ks] = *(const f16x8*)(QH + off);
    }

  f32x4 oacc[3][5];
#pragma unroll
  for (int mi = 0; mi < 3; ++mi)
#pragma unroll
    for (int nt = 0; nt < 5; ++nt) oacc[mi][nt] = (f32x4){0.f, 0.f, 0.f, 0.f};
  float lsum[3] = {0.f, 0.f, 0.f};   // all of a lane's p share i = mi*16+l15

  unsigned short* psw = u.ps[w];

  // per-jtile-advancing global bases (uniform)
  const unsigned short* kp = KH + ((size_t)b * NPIX + sp * JCHUNK) * CP;
  const unsigned short* vp = VG + (size_t)b * 80 * NPIX + sp * JCHUNK;

  for (int jt = 0; jt < JTILES; ++jt, kp += 64 * CP, vp += 64) {
    // ---- S^T scores (K frags direct from global) -> exp -> b64 P write ----
#pragma unroll
    for (int tj = 0; tj < 4; ++tj) {
      f16x8 fkh[3];
#pragma unroll
      for (int ks = 0; ks < 3; ++ks)
        fkh[ks] = *(const f16x8*)(kp + (tj * 16 + l15) * CP + ks * 32 + quad * 8);
#pragma unroll
      for (int mi = 0; mi < 3; ++mi) {
        f32x4 s = (f32x4){0.f, 0.f, 0.f, 0.f};
        s = MFMA_F16(fkh[0], qh[mi][0], s);   // A=K (m=j), B=Q (n=i)
        s = MFMA_F16(fkh[1], qh[mi][1], s);
        s = MFMA_F16(fkh[2], qh[mi][2], s);
        float p0 = __builtin_amdgcn_exp2f(__builtin_fmaf(s[0], L2E, -EXPB));
        float p1 = __builtin_amdgcn_exp2f(__builtin_fmaf(s[1], L2E, -EXPB));
        float p2 = __builtin_amdgcn_exp2f(__builtin_fmaf(s[2], L2E, -EXPB));
        float p3 = __builtin_amdgcn_exp2f(__builtin_fmaf(s[3], L2E, -EXPB));
        lsum[mi] += (p0 + p1) + (p2 + p3);
        uint2 pk;
        pk.x = pack_bf_trunc(p0, p1);
        pk.y = pack_bf_trunc(p2, p3);
        *(uint2*)(psw + (mi * 16 + l15) * PSP + tj * 16 + quad * 4) = pk;
      }
    }

    // ---- PV: own-wave P from LDS + V frags direct from global ----
#pragma unroll
    for (int js = 0; js < 2; ++js) {
      bf16x8 pf[3];
#pragma unroll
      for (int mi = 0; mi < 3; ++mi)
        pf[mi] = *(const bf16x8*)(psw + (mi * 16 + l15) * PSP + js * 32 + quad * 8);
#pragma unroll
      for (int nt = 0; nt < 5; ++nt) {
        bf16x8 vf = *(const bf16x8*)(vp + ((size_t)(nt * 16 + l15)) * NPIX +
                                     js * 32 + quad * 8);
#pragma unroll
        for (int mi = 0; mi < 3; ++mi)
          oacc[mi][nt] = MFMA_BF16(pf[mi], vf, oacc[mi][nt]);
      }
    }
    // no barrier: ps is wave-private, K/V are read-only global
  }

  // ---- epilogue: reduce l across quads, transpose O via LDS, store bf16 ----
  const size_t sb = (size_t)(sp * 2 + b);
#pragma unroll
  for (int mi = 0; mi < 3; ++mi) {
    float v = lsum[mi];
    v += __shfl_xor(v, 16);
    v += __shfl_xor(v, 32);
    if (quad == 0)
      LPART[sb * NPIX + i0w + mi * 16 + l15] = v;
  }

  float* slotp = u.eb[w];
#pragma unroll
  for (int mi = 0; mi < 3; ++mi) {
    __syncthreads();   // 1st iter: all waves past K-loop before eb overwrites ps
#pragma unroll
    for (int nt = 0; nt < 5; ++nt)
#pragma unroll
      for (int r = 0; r < 4; ++r) {
        int row = quad * 4 + r;        // n within 16-row tile
        int col = nt * 16 + l15;       // channel
        if (col < 72) slotp[row * 73 + col] = oacc[mi][nt][r];
      }
    __syncthreads();
#pragma unroll
    for (int cc = 0; cc < 18; ++cc) {
      int c = cc * 4 + quad;
      OPH[(sb * 72 + c) * NPIX + i0w + mi * 16 + l15] = f2bf(slotp[l15 * 73 + c]);
    }
  }
}

// ---------------------------------------------------------------------------
// Kernel 3: combine splits (shared scale -> plain sums) + factor-4 pooling.
// ---------------------------------------------------------------------------
__global__ __launch_bounds__(256) void combine_pool_kernel(
    const float* __restrict__ x, const unsigned short* __restrict__ OPH,
    const float* __restrict__ LPART, float* __restrict__ out)
{
  int id = blockIdx.x * 256 + threadIdx.x;
  if (id >= 2 * 18 * (NPIX / 4)) return;
  int n = (id % (NPIX / 4)) * 4;
  int rest = id / (NPIX / 4);
  int g = rest % 18, b = rest / 18;

  float4 L = make_float4(0.f, 0.f, 0.f, 0.f);
  float4 a0 = L, a1 = L, a2 = L, a3 = L;
#pragma unroll
  for (int s = 0; s < SPLITS; ++s) {
    size_t sb = (size_t)(s * 2 + b);
    float4 l4 = *(const float4*)(LPART + sb * NPIX + n);
    L.x += l4.x; L.y += l4.y; L.z += l4.z; L.w += l4.w;
    size_t base = (sb * 72 + g * 4) * NPIX + n;
    uint2 u0 = *(const uint2*)(OPH + base);
    uint2 u1 = *(const uint2*)(OPH + base + NPIX);
    uint2 u2 = *(const uint2*)(OPH + base + 2 * NPIX);
    uint2 u3 = *(const uint2*)(OPH + base + 3 * NPIX);
    a0.x += __uint_as_float(u0.x << 16); a0.y += __uint_as_float(u0.x & 0xffff0000u);
    a0.z += __uint_as_float(u0.y << 16); a0.w += __uint_as_float(u0.y & 0xffff0000u);
    a1.x += __uint_as_float(u1.x << 16); a1.y += __uint_as_float(u1.x & 0xffff0000u);
    a1.z += __uint_as_float(u1.y << 16); a1.w += __uint_as_float(u1.y & 0xffff0000u);
    a2.x += __uint_as_float(u2.x << 16); a2.y += __uint_as_float(u2.x & 0xffff0000u);
    a2.z += __uint_as_float(u2.y << 16); a2.w += __uint_as_float(u2.y & 0xffff0000u);
    a3.x += __uint_as_float(u3.x << 16); a3.y += __uint_as_float(u3.x & 0xffff0000u);
    a3.z += __uint_as_float(u3.y << 16); a3.w += __uint_as_float(u3.y & 0xffff0000u);
  }
  size_t xb = ((size_t)b * CIN + g * 4) * NPIX + n;
  float4 x0 = *(const float4*)(x + xb);
  float4 x1 = *(const float4*)(x + xb + NPIX);
  float4 x2 = *(const float4*)(x + xb + 2 * NPIX);
  float4 x3 = *(const float4*)(x + xb + 3 * NPIX);
  float4 r;
  r.x = (x0.x * a0.x + x1.x * a1.x + x2.x * a2.x + x3.x * a3.x) / L.x;
  r.y = (x0.y * a0.y + x1.y * a1.y + x2.y * a2.y + x3.y * a3.y) / L.y;
  r.z = (x0.z * a0.z + x1.z * a1.z + x2.z * a2.z + x3.z * a3.z) / L.z;
  r.w = (x0.w * a0.w + x1.w * a1.w + x2.w * a2.w + x3.w * a3.w) / L.w;
  *(float4*)(out + (size_t)id * 4) = r;
}

// ---------------------------------------------------------------------------
extern "C" void kernel_launch(void* const* d_in, const int* in_sizes, int n_in,
                              void* d_out, int out_size, void* d_ws, size_t ws_size,
                              hipStream_t stream) {
  const float* x  = (const float*)d_in[0];
  const float* Wq = (const float*)d_in[1];
  const float* bq = (const float*)d_in[2];
  const float* Wk = (const float*)d_in[3];
  const float* bk = (const float*)d_in[4];
  const float* Wv = (const float*)d_in[5];
  const float* bv = (const float*)d_in[6];
  float* out = (float*)d_out;

  char* p = (char*)d_ws;
  const size_t szQK = (size_t)2 * NPIX * CP * 2;
  unsigned short* QH = (unsigned short*)p; p += szQK;
  unsigned short* KH = (unsigned short*)p; p += szQK;
  unsigned short* VG = (unsigned short*)p; p += (size_t)2 * 80 * NPIX * 2;
  unsigned short* WH = (unsigned short*)p; p += (size_t)3 * 80 * 96 * 2;
  unsigned short* WL = (unsigned short*)p; p += (size_t)3 * 80 * 96 * 2;
  unsigned short* OPH = (unsigned short*)p; p += (size_t)SPLITS * 2 * 72 * NPIX * 2; // 21.2 MB
  float* LPART = (float*)p; p += (size_t)SPLITS * 2 * NPIX * 4;                      // 0.6 MB

  wprep_kernel<<<(3 * 80 * 96 + 255) / 256, 256, 0, stream>>>(Wq, Wk, Wv, WH, WL);
  qkv_kernel<<<1152, 64, 0, stream>>>(x, WH, WL, bq, bk, bv, QH, KH, VG);
  flash_kernel<<<768, 256, 0, stream>>>(QH, KH, VG, OPH, LPART);
  combine_pool_kernel<<<(2 * 18 * (NPIX / 4) + 255) / 256, 256, 0, stream>>>(
      x, OPH, LPART, out);
}

// Round 9
// 208.182 us; speedup vs baseline: 1.7710x; 1.7710x over previous
//
#include <hip/hip_runtime.h>

#define NPIX 9216
#define CIN 72
#define CP 96
#define SPLITS 8
#define JCHUNK (NPIX / SPLITS)   // 1152
#define JTILES (JCHUNK / 64)     // 18
// p = exp2(s*log2e - 32*log2e)  (fixed softmax shift 32; safe to s<120)
#define L2E   1.44269504088896f
#define EXPB  46.1662413084468f

typedef __attribute__((ext_vector_type(8))) short bf16x8;
typedef __attribute__((ext_vector_type(8))) _Float16 f16x8;
typedef __attribute__((ext_vector_type(4))) float f32x4;

#define MFMA_BF16(A,B,C) __builtin_amdgcn_mfma_f32_16x16x32_bf16(A,B,C,0,0,0)
#define MFMA_F16(A,B,C)  __builtin_amdgcn_mfma_f32_16x16x32_f16(A,B,C,0,0,0)

static __device__ __forceinline__ unsigned short f2bf(float f) {
  unsigned u = __float_as_uint(f);
  u += 0x7fffu + ((u >> 16) & 1u);
  return (unsigned short)(u >> 16);
}
static __device__ __forceinline__ float bf2f(unsigned short h) {
  return __uint_as_float(((unsigned)h) << 16);
}
static __device__ __forceinline__ unsigned short f2h(float f) {
  _Float16 h = (_Float16)f;
  return *(unsigned short*)&h;
}
// pack trunc-bf16 of (lo,hi) into one dword: [lo.hi16 | hi.hi16]
static __device__ __forceinline__ unsigned pack_bf_trunc(float lo, float hi) {
  return (__float_as_uint(lo) >> 16) | (__float_as_uint(hi) & 0xffff0000u);
}

// ---------------------------------------------------------------------------
// Kernel 0: W prep — split-bf16 (hi/lo) of Wq/Wk/Wv, padded to [80][96].
// ---------------------------------------------------------------------------
__global__ __launch_bounds__(256) void wprep_kernel(
    const float* __restrict__ Wq, const float* __restrict__ Wk,
    const float* __restrict__ Wv,
    unsigned short* __restrict__ WH, unsigned short* __restrict__ WL)
{
  int id = blockIdx.x * 256 + threadIdx.x;
  if (id >= 3 * 80 * 96) return;
  int mat = id / (80 * 96);
  int rem = id % (80 * 96);
  int d = rem / 96, c = rem % 96;
  const float* W = (mat == 0) ? Wq : (mat == 1) ? Wk : Wv;
  float v = (d < 72 && c < 72) ? W[d * 72 + c] : 0.f;
  unsigned short hi = f2bf(v);
  WH[id] = hi;
  WL[id] = f2bf(v - bf2f(hi));
}

// ---------------------------------------------------------------------------
// Kernel 1: QKV projection, split-bf16 MFMA GEMM, one wave per block (16 px).
// ---------------------------------------------------------------------------
#define XTS 104   // LDS row stride (ushorts), 208 B

__global__ __launch_bounds__(64) void qkv_kernel(
    const float* __restrict__ x,
    const unsigned short* __restrict__ WH, const unsigned short* __restrict__ WL,
    const float* __restrict__ bq, const float* __restrict__ bk,
    const float* __restrict__ bv,
    unsigned short* __restrict__ QH, unsigned short* __restrict__ KH,
    unsigned short* __restrict__ VG)
{
  __shared__ __align__(16) unsigned short xth[16 * XTS];
  __shared__ __align__(16) unsigned short xtl[16 * XTS];
  __shared__ __align__(16) unsigned short obuf[16 * XTS];

  const int t    = threadIdx.x;
  const int quad = t >> 4;
  const int l15  = t & 15;
  const int bid  = blockIdx.x;
  const int b    = bid / 576;
  const int n0   = (bid % 576) * 16;

  for (int e = t; e < 72 * 16; e += 64) {
    int c = e >> 4, px = e & 15;
    float f = x[((size_t)b * CIN + c) * NPIX + n0 + px];
    unsigned short hi = f2bf(f);
    xth[px * XTS + c] = hi;
    xtl[px * XTS + c] = f2bf(f - bf2f(hi));
  }
  for (int e = t; e < 24 * 16; e += 64) {
    int c = 72 + (e >> 4), px = e & 15;
    xth[px * XTS + c] = 0;
    xtl[px * XTS + c] = 0;
  }
  __syncthreads();

  bf16x8 xbh[3], xbl[3];
#pragma unroll
  for (int ks = 0; ks < 3; ++ks) {
    int off = l15 * XTS + ks * 32 + quad * 8;
    xbh[ks] = *(const bf16x8*)(xth + off);
    xbl[ks] = *(const bf16x8*)(xtl + off);
  }

  for (int mat = 0; mat < 3; ++mat) {
    const unsigned short* wh = WH + mat * 80 * 96;
    const unsigned short* wl = WL + mat * 80 * 96;
    const float* bias = (mat == 0) ? bq : (mat == 1) ? bk : bv;

    f32x4 acc[5];
#pragma unroll
    for (int dm = 0; dm < 5; ++dm) {
      acc[dm] = (f32x4){0.f, 0.f, 0.f, 0.f};
#pragma unroll
      for (int ks = 0; ks < 3; ++ks) {
        bf16x8 ah = *(const bf16x8*)(wh + (dm * 16 + l15) * 96 + ks * 32 + quad * 8);
        bf16x8 al = *(const bf16x8*)(wl + (dm * 16 + l15) * 96 + ks * 32 + quad * 8);
        acc[dm] = MFMA_BF16(ah, xbh[ks], acc[dm]);
        acc[dm] = MFMA_BF16(ah, xbl[ks], acc[dm]);
        acc[dm] = MFMA_BF16(al, xbh[ks], acc[dm]);
      }
    }

    if (mat < 2) {
      __syncthreads();                 // obuf free
#pragma unroll
      for (int dm = 0; dm < 5; ++dm)
#pragma unroll
        for (int r = 0; r < 4; ++r) {
          int d = dm * 16 + quad * 4 + r;
          float v = acc[dm][r] + (d < 72 ? bias[d] : 0.f);
          obuf[l15 * XTS + d] = f2h(v);
        }
      __syncthreads();
      unsigned short* outp = (mat == 0) ? QH : KH;
      const size_t ob = ((size_t)b * NPIX + n0) * CP;
      uint4 z; z.x = z.y = z.z = z.w = 0u;
      for (int f = t; f < 192; f += 64) {
        int row = f / 12, col = f % 12;
        *(uint4*)(outp + ob + (size_t)row * CP + col * 8) =
            (col < 10) ? *(const uint4*)(obuf + row * XTS + col * 8) : z;
      }
    } else {
#pragma unroll
      for (int dm = 0; dm < 5; ++dm)
#pragma unroll
        for (int r = 0; r < 4; ++r) {
          int d = dm * 16 + quad * 4 + r;
          float v = acc[dm][r] + (d < 72 ? bias[d] : 0.f);
          VG[((size_t)b * 80 + d) * NPIX + n0 + l15] = f2bf(v);
        }
    }
  }
}

// ---------------------------------------------------------------------------
// Kernel 2: fused flash attention — NO K/V LDS staging, NO K-loop barriers.
// K fragments (S^T A-operand) and V fragments (PV B-operand) are 16B-
// contiguous in the global KH[n][c] / VG[c][n] layouts -> direct global b128
// loads (16x64B fully-utilized transactions), served by XCD-affine L2 chunk
// (sp = bid&7, K 221 KB + V 184 KB resident) and L1. LDS holds only the
// per-wave P tiles (write b64 -> read b128, same wave, lgkmcnt only).
// Grid 768; 4 waves x 48 rows. waves=3 launch bound: the ONLY working reg
// config (waves=4 -> 128-reg budget -> catastrophic spill, measured R2+R8).
// ---------------------------------------------------------------------------
#define PSP 72    // p tile stride

__global__ __launch_bounds__(256, 3) void flash_kernel(
    const unsigned short* __restrict__ QH, const unsigned short* __restrict__ KH,
    const unsigned short* __restrict__ VG,
    unsigned short* __restrict__ OPH, float* __restrict__ LPART)
{
  __shared__ __align__(16) union {
    unsigned short ps[4][48 * PSP];  // 27,648 B (K-loop, per-wave slots)
    float eb[4][16 * 73];            // 18,688 B (epilogue only)
  } u;

  const int t    = threadIdx.x;
  const int w    = t >> 6;
  const int lane = t & 63;
  const int quad = lane >> 4;
  const int l15  = lane & 15;

  const int bid  = blockIdx.x;
  const int sp   = bid & 7;
  const int slot = bid >> 3;
  const int b    = slot / 48;
  const int it   = slot % 48;
  const int i0w  = it * 192 + w * 48;

  // Q fragments (B-operand of S^T scores: n=l15=i, k=quad*8+c)
  f16x8 qh[3][3];
#pragma unroll
  for (int mi = 0; mi < 3; ++mi)
#pragma unroll
    for (int ks = 0; ks < 3; ++ks) {
      size_t off = ((size_t)b * NPIX + i0w + mi * 16 + l15) * CP + ks * 32 + quad * 8;
      qh[mi][ks] = *(const f16x8*)(QH + off);
    }

  f32x4 oacc[3][5];
#pragma unroll
  for (int mi = 0; mi < 3; ++mi)
#pragma unroll
    for (int nt = 0; nt < 5; ++nt) oacc[mi][nt] = (f32x4){0.f, 0.f, 0.f, 0.f};
  float lsum[3] = {0.f, 0.f, 0.f};   // all of a lane's p share i = mi*16+l15

  unsigned short* psw = u.ps[w];

  // per-jtile-advancing global bases (uniform)
  const unsigned short* kp = KH + ((size_t)b * NPIX + sp * JCHUNK) * CP;
  const unsigned short* vp = VG + (size_t)b * 80 * NPIX + sp * JCHUNK;

  for (int jt = 0; jt < JTILES; ++jt, kp += 64 * CP, vp += 64) {
    // ---- S^T scores (K frags direct from global) -> exp -> b64 P write ----
#pragma unroll
    for (int tj = 0; tj < 4; ++tj) {
      f16x8 fkh[3];
#pragma unroll
      for (int ks = 0; ks < 3; ++ks)
        fkh[ks] = *(const f16x8*)(kp + (tj * 16 + l15) * CP + ks * 32 + quad * 8);
#pragma unroll
      for (int mi = 0; mi < 3; ++mi) {
        f32x4 s = (f32x4){0.f, 0.f, 0.f, 0.f};
        s = MFMA_F16(fkh[0], qh[mi][0], s);   // A=K (m=j), B=Q (n=i)
        s = MFMA_F16(fkh[1], qh[mi][1], s);
        s = MFMA_F16(fkh[2], qh[mi][2], s);
        float p0 = __builtin_amdgcn_exp2f(__builtin_fmaf(s[0], L2E, -EXPB));
        float p1 = __builtin_amdgcn_exp2f(__builtin_fmaf(s[1], L2E, -EXPB));
        float p2 = __builtin_amdgcn_exp2f(__builtin_fmaf(s[2], L2E, -EXPB));
        float p3 = __builtin_amdgcn_exp2f(__builtin_fmaf(s[3], L2E, -EXPB));
        lsum[mi] += (p0 + p1) + (p2 + p3);
        uint2 pk;
        pk.x = pack_bf_trunc(p0, p1);
        pk.y = pack_bf_trunc(p2, p3);
        *(uint2*)(psw + (mi * 16 + l15) * PSP + tj * 16 + quad * 4) = pk;
      }
    }

    // ---- PV: own-wave P from LDS + V frags direct from global ----
#pragma unroll
    for (int js = 0; js < 2; ++js) {
      bf16x8 pf[3];
#pragma unroll
      for (int mi = 0; mi < 3; ++mi)
        pf[mi] = *(const bf16x8*)(psw + (mi * 16 + l15) * PSP + js * 32 + quad * 8);
#pragma unroll
      for (int nt = 0; nt < 5; ++nt) {
        bf16x8 vf = *(const bf16x8*)(vp + ((size_t)(nt * 16 + l15)) * NPIX +
                                     js * 32 + quad * 8);
#pragma unroll
        for (int mi = 0; mi < 3; ++mi)
          oacc[mi][nt] = MFMA_BF16(pf[mi], vf, oacc[mi][nt]);
      }
    }
    // no barrier: ps is wave-private, K/V are read-only global
  }

  // ---- epilogue: reduce l across quads, transpose O via LDS, store bf16 ----
  const size_t sb = (size_t)(sp * 2 + b);
#pragma unroll
  for (int mi = 0; mi < 3; ++mi) {
    float v = lsum[mi];
    v += __shfl_xor(v, 16);
    v += __shfl_xor(v, 32);
    if (quad == 0)
      LPART[sb * NPIX + i0w + mi * 16 + l15] = v;
  }

  float* slotp = u.eb[w];
#pragma unroll
  for (int mi = 0; mi < 3; ++mi) {
    __syncthreads();   // 1st iter: all waves past K-loop before eb overwrites ps
#pragma unroll
    for (int nt = 0; nt < 5; ++nt)
#pragma unroll
      for (int r = 0; r < 4; ++r) {
        int row = quad * 4 + r;        // n within 16-row tile
        int col = nt * 16 + l15;       // channel
        if (col < 72) slotp[row * 73 + col] = oacc[mi][nt][r];
      }
    __syncthreads();
#pragma unroll
    for (int cc = 0; cc < 18; ++cc) {
      int c = cc * 4 + quad;
      OPH[(sb * 72 + c) * NPIX + i0w + mi * 16 + l15] = f2bf(slotp[l15 * 73 + c]);
    }
  }
}

// ---------------------------------------------------------------------------
// Kernel 3: combine splits (shared scale -> plain sums) + factor-4 pooling.
// ---------------------------------------------------------------------------
__global__ __launch_bounds__(256) void combine_pool_kernel(
    const float* __restrict__ x, const unsigned short* __restrict__ OPH,
    const float* __restrict__ LPART, float* __restrict__ out)
{
  int id = blockIdx.x * 256 + threadIdx.x;
  if (id >= 2 * 18 * (NPIX / 4)) return;
  int n = (id % (NPIX / 4)) * 4;
  int rest = id / (NPIX / 4);
  int g = rest % 18, b = rest / 18;

  float4 L = make_float4(0.f, 0.f, 0.f, 0.f);
  float4 a0 = L, a1 = L, a2 = L, a3 = L;
#pragma unroll
  for (int s = 0; s < SPLITS; ++s) {
    size_t sb = (size_t)(s * 2 + b);
    float4 l4 = *(const float4*)(LPART + sb * NPIX + n);
    L.x += l4.x; L.y += l4.y; L.z += l4.z; L.w += l4.w;
    size_t base = (sb * 72 + g * 4) * NPIX + n;
    uint2 u0 = *(const uint2*)(OPH + base);
    uint2 u1 = *(const uint2*)(OPH + base + NPIX);
    uint2 u2 = *(const uint2*)(OPH + base + 2 * NPIX);
    uint2 u3 = *(const uint2*)(OPH + base + 3 * NPIX);
    a0.x += __uint_as_float(u0.x << 16); a0.y += __uint_as_float(u0.x & 0xffff0000u);
    a0.z += __uint_as_float(u0.y << 16); a0.w += __uint_as_float(u0.y & 0xffff0000u);
    a1.x += __uint_as_float(u1.x << 16); a1.y += __uint_as_float(u1.x & 0xffff0000u);
    a1.z += __uint_as_float(u1.y << 16); a1.w += __uint_as_float(u1.y & 0xffff0000u);
    a2.x += __uint_as_float(u2.x << 16); a2.y += __uint_as_float(u2.x & 0xffff0000u);
    a2.z += __uint_as_float(u2.y << 16); a2.w += __uint_as_float(u2.y & 0xffff0000u);
    a3.x += __uint_as_float(u3.x << 16); a3.y += __uint_as_float(u3.x & 0xffff0000u);
    a3.z += __uint_as_float(u3.y << 16); a3.w += __uint_as_float(u3.y & 0xffff0000u);
  }
  size_t xb = ((size_t)b * CIN + g * 4) * NPIX + n;
  float4 x0 = *(const float4*)(x + xb);
  float4 x1 = *(const float4*)(x + xb + NPIX);
  float4 x2 = *(const float4*)(x + xb + 2 * NPIX);
  float4 x3 = *(const float4*)(x + xb + 3 * NPIX);
  float4 r;
  r.x = (x0.x * a0.x + x1.x * a1.x + x2.x * a2.x + x3.x * a3.x) / L.x;
  r.y = (x0.y * a0.y + x1.y * a1.y + x2.y * a2.y + x3.y * a3.y) / L.y;
  r.z = (x0.z * a0.z + x1.z * a1.z + x2.z * a2.z + x3.z * a3.z) / L.z;
  r.w = (x0.w * a0.w + x1.w * a1.w + x2.w * a2.w + x3.w * a3.w) / L.w;
  *(float4*)(out + (size_t)id * 4) = r;
}

// ---------------------------------------------------------------------------
extern "C" void kernel_launch(void* const* d_in, const int* in_sizes, int n_in,
                              void* d_out, int out_size, void* d_ws, size_t ws_size,
                              hipStream_t stream) {
  const float* x  = (const float*)d_in[0];
  const float* Wq = (const float*)d_in[1];
  const float* bq = (const float*)d_in[2];
  const float* Wk = (const float*)d_in[3];
  const float* bk = (const float*)d_in[4];
  const float* Wv = (const float*)d_in[5];
  const float* bv = (const float*)d_in[6];
  float* out = (float*)d_out;

  char* p = (char*)d_ws;
  const size_t szQK = (size_t)2 * NPIX * CP * 2;
  unsigned short* QH = (unsigned short*)p; p += szQK;
  unsigned short* KH = (unsigned short*)p; p += szQK;
  unsigned short* VG = (unsigned short*)p; p += (size_t)2 * 80 * NPIX * 2;
  unsigned short* WH = (unsigned short*)p; p += (size_t)3 * 80 * 96 * 2;
  unsigned short* WL = (unsigned short*)p; p += (size_t)3 * 80 * 96 * 2;
  unsigned short* OPH = (unsigned short*)p; p += (size_t)SPLITS * 2 * 72 * NPIX * 2; // 21.2 MB
  float* LPART = (float*)p; p += (size_t)SPLITS * 2 * NPIX * 4;                      // 0.6 MB

  wprep_kernel<<<(3 * 80 * 96 + 255) / 256, 256, 0, stream>>>(Wq, Wk, Wv, WH, WL);
  qkv_kernel<<<1152, 64, 0, stream>>>(x, WH, WL, bq, bk, bv, QH, KH, VG);
  flash_kernel<<<768, 256, 0, stream>>>(QH, KH, VG, OPH, LPART);
  combine_pool_kernel<<<(2 * 18 * (NPIX / 4) + 255) / 256, 256, 0, stream>>>(
      x, OPH, LPART, out);
}